// Round 4
// baseline (1110.574 us; speedup 1.0000x reference)
//
#include <hip/hip_runtime.h>
#include <math.h>

#define HN 128
#define NC 8
#define EPSV 1e-5f
#define SLOPEV 0.01f

typedef __attribute__((ext_vector_type(4))) float f32x4;
typedef __attribute__((ext_vector_type(8))) short bf16x8;

__device__ __forceinline__ uint bf16rne(float f) {
    uint u = __float_as_uint(f);
    return (u + 0x7fffu + ((u >> 16) & 1u)) >> 16;
}

// ---------------- degree count ----------------
__global__ void deg_kernel(const int* __restrict__ src, const int* __restrict__ dst,
                           int* __restrict__ degO, int* __restrict__ degI, int E) {
    int e = blockIdx.x * blockDim.x + threadIdx.x;
    if (e < E) {
        atomicAdd(&degO[src[e]], 1);
        atomicAdd(&degI[dst[e]], 1);
    }
}

// ---------------- hierarchical exclusive scan ----------------
__global__ __launch_bounds__(256) void scan_partial(const int* __restrict__ degI,
                                                    int* __restrict__ blockSums, int n) {
    __shared__ int sS[256];
    int tid = threadIdx.x;
    int base = blockIdx.x * 1024 + tid * 4;
    int s = 0;
    #pragma unroll
    for (int j = 0; j < 4; j++) {
        int idx = base + j;
        s += (idx < n) ? degI[idx] : 0;
    }
    sS[tid] = s;
    __syncthreads();
    for (int off = 128; off; off >>= 1) {
        if (tid < off) sS[tid] += sS[tid + off];
        __syncthreads();
    }
    if (tid == 0) blockSums[blockIdx.x] = sS[0];
}

__global__ __launch_bounds__(1024) void scan_blocksums(int* __restrict__ blockSums, int nb) {
    __shared__ int sS[1024];
    int tid = threadIdx.x;
    int v = (tid < nb) ? blockSums[tid] : 0;
    sS[tid] = v;
    __syncthreads();
    for (int off = 1; off < 1024; off <<= 1) {
        int t = (tid >= off) ? sS[tid - off] : 0;
        __syncthreads();
        sS[tid] += t;
        __syncthreads();
    }
    if (tid < nb) blockSums[tid] = sS[tid] - v;
}

__global__ __launch_bounds__(256) void scan_final(const int* __restrict__ degI,
                                                  const int* __restrict__ blockSums,
                                                  int* __restrict__ row_ptr,
                                                  int* __restrict__ cursor, int n, int E) {
    __shared__ int sS[256];
    int tid = threadIdx.x;
    int base = blockIdx.x * 1024 + tid * 4;
    int v[4];
    int tot = 0;
    #pragma unroll
    for (int j = 0; j < 4; j++) {
        int idx = base + j;
        int vv = (idx < n) ? degI[idx] : 0;
        v[j] = tot;
        tot += vv;
    }
    sS[tid] = tot;
    __syncthreads();
    for (int off = 1; off < 256; off <<= 1) {
        int t = (tid >= off) ? sS[tid - off] : 0;
        __syncthreads();
        sS[tid] += t;
        __syncthreads();
    }
    int tb = blockSums[blockIdx.x] + sS[tid] - tot;
    #pragma unroll
    for (int j = 0; j < 4; j++) {
        int idx = base + j;
        if (idx < n) {
            int rp = tb + v[j];
            row_ptr[idx] = rp;
            cursor[idx] = rp;
        }
    }
    if (blockIdx.x == 0 && tid == 0) row_ptr[n] = E;
}

// ---------------- norms ----------------
__global__ void norm_kernel(const int* __restrict__ degO, const int* __restrict__ degI,
                            float* __restrict__ onorm, float* __restrict__ inorm, int n) {
    int i = blockIdx.x * blockDim.x + threadIdx.x;
    if (i < n) {
        float a = (float)degO[i]; if (a < 1.f) a = 1.f;
        float b = (float)degI[i]; if (b < 1.f) b = 1.f;
        onorm[i] = rsqrtf(a);
        inorm[i] = rsqrtf(b);
    }
}

// ---------------- CSR src-value scatter ----------------
__global__ void src_scatter(const int* __restrict__ src, const int* __restrict__ dst,
                            int* __restrict__ cursor, int* __restrict__ srcs, int E) {
    int e = blockIdx.x * blockDim.x + threadIdx.x;
    if (e < E) {
        int p = atomicAdd(&cursor[dst[e]], 1);
        srcs[p] = src[e];
    }
}

// ---------------- weight prep: W[k][n] -> WT[n][k] hi/lo bf16 (4 layers) ----------------
__global__ __launch_bounds__(256) void wprep_kernel(
        const float* __restrict__ W1, const float* __restrict__ W2,
        const float* __restrict__ W3, const float* __restrict__ W4,
        ushort* __restrict__ WTh, ushort* __restrict__ WTl) {
    int i = blockIdx.x * blockDim.x + threadIdx.x;   // 4*16384
    int l = i >> 14, r = i & 16383;
    int k = r >> 7, nn = r & 127;
    const float* W = (l == 0) ? W1 : (l == 1) ? W2 : (l == 2) ? W3 : W4;
    float w = W[k * HN + nn];
    uint hi = bf16rne(w);
    float fhi = __uint_as_float(hi << 16);
    uint lo = bf16rne(w - fhi);
    WTh[(size_t)l * 16384 + nn * HN + k] = (ushort)hi;
    WTl[(size_t)l * 16384 + nn * HN + k] = (ushort)lo;
}

// ---------------- pack: fp32 * onorm -> bf16 (layer-1 input) ----------------
__global__ __launch_bounds__(256) void pack_kernel(
        const float* __restrict__ in, const float* __restrict__ onorm,
        ushort* __restrict__ out, int total4) {
    int i = blockIdx.x * blockDim.x + threadIdx.x;
    if (i >= total4) return;
    float w = onorm[i >> 5];
    float4 v = ((const float4*)in)[i];
    ushort4 o = make_ushort4((ushort)bf16rne(v.x * w), (ushort)bf16rne(v.y * w),
                             (ushort)bf16rne(v.z * w), (ushort)bf16rne(v.w * w));
    *(ushort4*)(out + (size_t)i * 4) = o;
}

// ---------------- fused BN-apply + lrelu + onorm-fold + bf16 pack ----------------
__global__ __launch_bounds__(256) void bnpack_kernel(
        const float* __restrict__ in, ushort* __restrict__ out,
        const float* __restrict__ scale, const float* __restrict__ shift,
        const float* __restrict__ onorm, int total4) {
    int i = blockIdx.x * blockDim.x + threadIdx.x;
    if (i >= total4) return;
    int cp = (i & 31) << 2;
    float w = onorm[i >> 5];
    float4 v = ((const float4*)in)[i];
    float4 s = *(const float4*)(scale + cp);
    float4 t = *(const float4*)(shift + cp);
    float h0 = fmaf(v.x, s.x, t.x); h0 = (h0 >= 0.f) ? h0 : SLOPEV * h0;
    float h1 = fmaf(v.y, s.y, t.y); h1 = (h1 >= 0.f) ? h1 : SLOPEV * h1;
    float h2 = fmaf(v.z, s.z, t.z); h2 = (h2 >= 0.f) ? h2 : SLOPEV * h2;
    float h3 = fmaf(v.w, s.w, t.w); h3 = (h3 >= 0.f) ? h3 : SLOPEV * h3;
    ushort4 o = make_ushort4((ushort)bf16rne(h0 * w), (ushort)bf16rne(h1 * w),
                             (ushort)bf16rne(h2 * w), (ushort)bf16rne(h3 * w));
    *(ushort4*)(out + (size_t)i * 4) = o;
}

// ---------------- aggregation: one wave per dst node, bf16 in, bf16 out ----------------
// out[i,:] = bf16( in_norm[i] * sum_{p} xb[srcs[p], :] )
__global__ __launch_bounds__(256) void agg_kernel(
        const uint* __restrict__ xb, uint* __restrict__ out,
        const int* __restrict__ srcs, const int* __restrict__ row_ptr,
        const float* __restrict__ inorm, int n) {
    int node = blockIdx.x * 4 + (threadIdx.x >> 6);
    if (node >= n) return;
    int lane = threadIdx.x & 63;
    int rp0 = row_ptr[node], rp1 = row_ptr[node + 1];
    float accx = 0.f, accy = 0.f;
    int j = rp0;
    for (; j + 1 < rp1; j += 2) {
        int s0 = srcs[j], s1 = srcs[j + 1];
        uint u0 = xb[(size_t)s0 * 64 + lane];
        uint u1 = xb[(size_t)s1 * 64 + lane];
        accx += __uint_as_float(u0 << 16) + __uint_as_float(u1 << 16);
        accy += __uint_as_float(u0 & 0xffff0000u) + __uint_as_float(u1 & 0xffff0000u);
    }
    if (j < rp1) {
        uint u0 = xb[(size_t)srcs[j] * 64 + lane];
        accx += __uint_as_float(u0 << 16);
        accy += __uint_as_float(u0 & 0xffff0000u);
    }
    float wi = inorm[node];
    uint o = bf16rne(accx * wi) | (bf16rne(accy * wi) << 16);
    out[(size_t)node * 64 + lane] = o;
}

// ---------------- MFMA GEMM: [n,128]bf16 @ (Whi+Wlo)[128,128] + b ----------------
// block = 4 waves; wave w: rows blockIdx*64 + 16w .. +15, all 128 cols.
// WT layout: WT[n][k] bf16 (i.e. W transposed), hi/lo split for accuracy.
// D layout per 16x16 tile: col = lane&15, row = (lane>>4)*4 + reg.
template<int DO_STATS, int DO_LRELU, int DO_PACK>
__global__ __launch_bounds__(256) void gemm_mfma(
        const ushort* __restrict__ A, const ushort* __restrict__ WTh,
        const ushort* __restrict__ WTl, const float* __restrict__ bias,
        void* __restrict__ outv, float* __restrict__ colsum, float* __restrict__ colsq,
        const float* __restrict__ onorm, int n) {
    __shared__ float sSum[4 * 128];
    __shared__ float sSq[4 * 128];
    int tid = threadIdx.x;
    int wave = tid >> 6, lane = tid & 63;
    int l15 = lane & 15, quad = lane >> 4;
    int rbase = blockIdx.x * 64 + wave * 16;
    int arow = rbase + l15; if (arow > n - 1) arow = n - 1;   // clamped safe load
    int kq = quad * 8;

    bf16x8 af[4];
    #pragma unroll
    for (int kc = 0; kc < 4; kc++)
        af[kc] = *(const bf16x8*)(A + (size_t)arow * HN + kc * 32 + kq);

    f32x4 acc[8];
    #pragma unroll
    for (int t = 0; t < 8; t++) acc[t] = (f32x4){0.f, 0.f, 0.f, 0.f};

    #pragma unroll
    for (int t = 0; t < 8; t++) {
        const ushort* bh = WTh + (size_t)(t * 16 + l15) * HN + kq;
        const ushort* bl = WTl + (size_t)(t * 16 + l15) * HN + kq;
        #pragma unroll
        for (int kc = 0; kc < 4; kc++) {
            bf16x8 b0 = *(const bf16x8*)(bh + kc * 32);
            acc[t] = __builtin_amdgcn_mfma_f32_16x16x32_bf16(af[kc], b0, acc[t], 0, 0, 0);
        }
        #pragma unroll
        for (int kc = 0; kc < 4; kc++) {
            bf16x8 b1 = *(const bf16x8*)(bl + kc * 32);
            acc[t] = __builtin_amdgcn_mfma_f32_16x16x32_bf16(af[kc], b1, acc[t], 0, 0, 0);
        }
    }

    #pragma unroll
    for (int t = 0; t < 8; t++) {
        int col = t * 16 + l15;
        float bv = bias[col];
        float s = 0.f, q = 0.f;
        #pragma unroll
        for (int i = 0; i < 4; i++) {
            int row = rbase + quad * 4 + i;
            float v = acc[t][i] + bv;
            if (DO_LRELU) v = (v >= 0.f) ? v : SLOPEV * v;
            if (row < n) {
                if (DO_PACK) {
                    ((ushort*)outv)[(size_t)row * HN + col] = (ushort)bf16rne(v * onorm[row]);
                } else {
                    ((float*)outv)[(size_t)row * HN + col] = v;
                }
                if (DO_STATS) { s += v; q += v * v; }
            }
        }
        if (DO_STATS) {
            s += __shfl_xor(s, 16); q += __shfl_xor(q, 16);
            s += __shfl_xor(s, 32); q += __shfl_xor(q, 32);
            if (quad == 0) { sSum[wave * 128 + col] = s; sSq[wave * 128 + col] = q; }
        }
    }
    if (DO_STATS) {
        __syncthreads();
        if (tid < 128) {
            float s = sSum[tid] + sSum[128 + tid] + sSum[256 + tid] + sSum[384 + tid];
            float q = sSq[tid] + sSq[128 + tid] + sSq[256 + tid] + sSq[384 + tid];
            atomicAdd(&colsum[tid], s);
            atomicAdd(&colsq[tid], q);
        }
    }
}

// ---------------- BN finalize ----------------
__global__ void bn_finalize(const float* __restrict__ colsum, const float* __restrict__ colsq,
                            const float* __restrict__ gamma, const float* __restrict__ beta,
                            float* __restrict__ scale, float* __restrict__ shift, int n) {
    int c = threadIdx.x;
    if (c < HN) {
        float inv = 1.f / (float)n;
        float mean = colsum[c] * inv;
        float var = colsq[c] * inv - mean * mean;
        if (var < 0.f) var = 0.f;
        float s = gamma[c] * rsqrtf(var + EPSV);
        scale[c] = s;
        shift[c] = beta[c] - mean * s;
    }
}

// ---------------- classifier: [n,128]fp32 @ [128,8]+bc ----------------
__global__ __launch_bounds__(256) void classifier_kernel(
        const float* __restrict__ A, const float* __restrict__ Wc,
        const float* __restrict__ bc, float* __restrict__ out, int n) {
    __shared__ float sW[HN * NC];
    __shared__ float sA[32 * 132];
    int tid = threadIdx.x;
    for (int i = tid; i < HN * NC; i += 256) sW[i] = Wc[i];
    int row0 = blockIdx.x * 32;
    for (int i = tid; i < 32 * 32; i += 256) {
        int r = i >> 5, c4 = (i & 31) << 2;
        float4 v = (row0 + r < n) ? *(const float4*)(A + (size_t)(row0 + r) * HN + c4)
                                  : make_float4(0.f, 0.f, 0.f, 0.f);
        *(float4*)&sA[r * 132 + c4] = v;
    }
    __syncthreads();
    int r = tid >> 3, c = tid & 7;
    float acc = 0.f;
    #pragma unroll 8
    for (int k = 0; k < HN; k++) acc = fmaf(sA[r * 132 + k], sW[k * NC + c], acc);
    int row = row0 + r;
    if (row < n) out[(size_t)row * NC + c] = acc + bc[c];
}

extern "C" void kernel_launch(void* const* d_in, const int* in_sizes, int n_in,
                              void* d_out, int out_size, void* d_ws, size_t ws_size,
                              hipStream_t stream) {
    const float* node_feat = (const float*)d_in[0];
    const int*   src    = (const int*)d_in[1];
    const int*   dst    = (const int*)d_in[2];
    const float* W1     = (const float*)d_in[3];
    const float* b1     = (const float*)d_in[4];
    const float* W2     = (const float*)d_in[5];
    const float* b2     = (const float*)d_in[6];
    const float* gamma1 = (const float*)d_in[7];
    const float* beta1  = (const float*)d_in[8];
    const float* gamma2 = (const float*)d_in[9];
    const float* beta2  = (const float*)d_in[10];
    const float* Wn1    = (const float*)d_in[11];
    const float* bn1    = (const float*)d_in[12];
    const float* Wn2    = (const float*)d_in[13];
    const float* bn2    = (const float*)d_in[14];
    const float* Wc     = (const float*)d_in[15];
    const float* bc     = (const float*)d_in[16];
    float* out = (float*)d_out;

    const int N = in_sizes[0] / HN;
    const int E = in_sizes[1];

    char* p = (char*)d_ws;
    float* bufA  = (float*)p; p += (size_t)N * HN * 4;   // lo half: HbA(bf16), hi half: Abf(bf16)
    float* bufB  = (float*)p; p += (size_t)N * HN * 4;   // fp32 gemm out / HbB(bf16)
    float* onorm = (float*)p; p += (size_t)N * 4;
    float* inorm = (float*)p; p += (size_t)N * 4;
    float* scale = (float*)p; p += HN * 4;
    float* shift = (float*)p; p += HN * 4;
    char* zbase = p;
    float* cs1 = (float*)p; p += HN * 4;
    float* cq1 = (float*)p; p += HN * 4;
    float* cs2 = (float*)p; p += HN * 4;
    float* cq2 = (float*)p; p += HN * 4;
    int* degO = (int*)p; p += (size_t)N * 4;
    int* degI = (int*)p; p += (size_t)N * 4;
    size_t zbytes = (size_t)(p - zbase);
    int* row_ptr = (int*)p; p += (size_t)(N + 1) * 4;
    int* cursor  = (int*)p; p += (size_t)N * 4;
    int* blockSums = (int*)p; p += 1024 * 4;
    int* srcs    = (int*)p; p += (size_t)E * 4;
    ushort* WTh  = (ushort*)p; p += 4 * 16384 * 2;
    ushort* WTl  = (ushort*)p; p += 4 * 16384 * 2;
    if ((size_t)(p - (char*)d_ws) > ws_size) return;

    hipMemsetAsync(zbase, 0, zbytes, stream);

    int gE = (E + 255) / 256, gN = (N + 255) / 256;
    int nb = (N + 1023) / 1024;
    deg_kernel<<<gE, 256, 0, stream>>>(src, dst, degO, degI, E);
    scan_partial<<<nb, 256, 0, stream>>>(degI, blockSums, N);
    scan_blocksums<<<1, 1024, 0, stream>>>(blockSums, nb);
    scan_final<<<nb, 256, 0, stream>>>(degI, blockSums, row_ptr, cursor, N, E);
    norm_kernel<<<gN, 256, 0, stream>>>(degO, degI, onorm, inorm, N);
    src_scatter<<<gE, 256, 0, stream>>>(src, dst, cursor, srcs, E);
    wprep_kernel<<<256, 256, 0, stream>>>(W1, W2, Wn1, Wn2, WTh, WTl);

    int gAgg = (N + 3) / 4;
    int gGemm = (N + 63) / 64;
    int gApply = (N * 32 + 255) / 256;

    ushort* HbA = (ushort*)bufA;                          // bufA lo half
    ushort* Abf = (ushort*)bufA + (size_t)N * HN;         // bufA hi half
    ushort* HbB = (ushort*)bufB;                          // bufB lo half

    // L1: pack -> HbA; agg -> Abf(bf16); mfma-gemm(stats) -> bufB fp32; bnpack -> HbA
    pack_kernel<<<gApply, 256, 0, stream>>>(node_feat, onorm, HbA, N * 32);
    agg_kernel<<<gAgg, 256, 0, stream>>>((const uint*)HbA, (uint*)Abf, srcs, row_ptr, inorm, N);
    gemm_mfma<1, 0, 0><<<gGemm, 256, 0, stream>>>(Abf, WTh, WTl, b1, bufB, cs1, cq1, nullptr, N);
    bn_finalize<<<1, 128, 0, stream>>>(cs1, cq1, gamma1, beta1, scale, shift, N);
    bnpack_kernel<<<gApply, 256, 0, stream>>>(bufB, HbA, scale, shift, onorm, N * 32);

    // L2
    agg_kernel<<<gAgg, 256, 0, stream>>>((const uint*)HbA, (uint*)Abf, srcs, row_ptr, inorm, N);
    gemm_mfma<1, 0, 0><<<gGemm, 256, 0, stream>>>(Abf, WTh + 16384, WTl + 16384, b2, bufB, cs2, cq2, nullptr, N);
    bn_finalize<<<1, 128, 0, stream>>>(cs2, cq2, gamma2, beta2, scale, shift, N);
    bnpack_kernel<<<gApply, 256, 0, stream>>>(bufB, HbA, scale, shift, onorm, N * 32);

    // L3: agg -> Abf; gemm(lrelu, pack*onorm) -> HbB(bf16)
    agg_kernel<<<gAgg, 256, 0, stream>>>((const uint*)HbA, (uint*)Abf, srcs, row_ptr, inorm, N);
    gemm_mfma<0, 1, 1><<<gGemm, 256, 0, stream>>>(Abf, WTh + 2 * 16384, WTl + 2 * 16384, bn1, HbB, nullptr, nullptr, onorm, N);

    // L4: agg(HbB) -> Abf; gemm(lrelu) -> bufB fp32; classifier
    agg_kernel<<<gAgg, 256, 0, stream>>>((const uint*)HbB, (uint*)Abf, srcs, row_ptr, inorm, N);
    gemm_mfma<0, 1, 0><<<gGemm, 256, 0, stream>>>(Abf, WTh + 3 * 16384, WTl + 3 * 16384, bn2, bufB, nullptr, nullptr, nullptr, N);
    classifier_kernel<<<(N + 31) / 32, 256, 0, stream>>>(bufB, Wc, bc, out, N);
}

// Round 5
// 922.690 us; speedup vs baseline: 1.2036x; 1.2036x over previous
//
#include <hip/hip_runtime.h>
#include <math.h>

#define HN 128
#define NC 8
#define EPSV 1e-5f
#define SLOPEV 0.01f

typedef __attribute__((ext_vector_type(4))) float f32x4;
typedef __attribute__((ext_vector_type(8))) short bf16x8;

__device__ __forceinline__ uint bf16rne(float f) {
    uint u = __float_as_uint(f);
    return (u + 0x7fffu + ((u >> 16) & 1u)) >> 16;
}

// ---------------- rank: degO histogram + in-count (doubles as rank) ----------------
__global__ void rank_kernel(const int* __restrict__ src, const int* __restrict__ dst,
                            int* __restrict__ degO, int* __restrict__ cntI,
                            int* __restrict__ rnk, int E) {
    int e = blockIdx.x * blockDim.x + threadIdx.x;
    if (e < E) {
        atomicAdd(&degO[src[e]], 1);
        rnk[e] = atomicAdd(&cntI[dst[e]], 1);
    }
}

// ---------------- hierarchical exclusive scan (3 kernels) ----------------
__global__ __launch_bounds__(256) void scan_partial(const int* __restrict__ degI,
                                                    int* __restrict__ blockSums, int n) {
    __shared__ int sS[256];
    int tid = threadIdx.x;
    int base = blockIdx.x * 1024 + tid * 4;
    int s = 0;
    #pragma unroll
    for (int j = 0; j < 4; j++) {
        int idx = base + j;
        s += (idx < n) ? degI[idx] : 0;
    }
    sS[tid] = s;
    __syncthreads();
    for (int off = 128; off; off >>= 1) {
        if (tid < off) sS[tid] += sS[tid + off];
        __syncthreads();
    }
    if (tid == 0) blockSums[blockIdx.x] = sS[0];
}

__global__ __launch_bounds__(1024) void scan_blocksums(int* __restrict__ blockSums, int nb) {
    __shared__ int sS[1024];
    int tid = threadIdx.x;
    int v = (tid < nb) ? blockSums[tid] : 0;
    sS[tid] = v;
    __syncthreads();
    for (int off = 1; off < 1024; off <<= 1) {
        int t = (tid >= off) ? sS[tid - off] : 0;
        __syncthreads();
        sS[tid] += t;
        __syncthreads();
    }
    if (tid < nb) blockSums[tid] = sS[tid] - v;
}

// local scan + block offset -> row_ptr; also computes norms (folded norm_kernel)
__global__ __launch_bounds__(256) void scan_final(const int* __restrict__ degI,
                                                  const int* __restrict__ degO,
                                                  const int* __restrict__ blockSums,
                                                  int* __restrict__ row_ptr,
                                                  float* __restrict__ onorm,
                                                  float* __restrict__ inorm, int n, int E) {
    __shared__ int sS[256];
    int tid = threadIdx.x;
    int base = blockIdx.x * 1024 + tid * 4;
    int v[4];
    int tot = 0;
    #pragma unroll
    for (int j = 0; j < 4; j++) {
        int idx = base + j;
        int vv = (idx < n) ? degI[idx] : 0;
        v[j] = tot;
        tot += vv;
    }
    sS[tid] = tot;
    __syncthreads();
    for (int off = 1; off < 256; off <<= 1) {
        int t = (tid >= off) ? sS[tid - off] : 0;
        __syncthreads();
        sS[tid] += t;
        __syncthreads();
    }
    int tb = blockSums[blockIdx.x] + sS[tid] - tot;
    #pragma unroll
    for (int j = 0; j < 4; j++) {
        int idx = base + j;
        if (idx < n) {
            row_ptr[idx] = tb + v[j];
            float a = (float)degO[idx]; if (a < 1.f) a = 1.f;
            float b = (float)degI[idx]; if (b < 1.f) b = 1.f;
            onorm[idx] = rsqrtf(a);
            inorm[idx] = rsqrtf(b);
        }
    }
    if (blockIdx.x == 0 && tid == 0) row_ptr[n] = E;
}

// ---------------- atomic-free CSR scatter ----------------
__global__ void scatter_kernel(const int* __restrict__ src, const int* __restrict__ dst,
                               const int* __restrict__ rnk, const int* __restrict__ row_ptr,
                               int* __restrict__ srcs, int E) {
    int e = blockIdx.x * blockDim.x + threadIdx.x;
    if (e < E) {
        int d = dst[e];
        srcs[row_ptr[d] + rnk[e]] = src[e];
    }
}

// ---------------- weight prep: W[k][n] -> WT[n][k] hi/lo bf16 (4 layers) ----------------
__global__ __launch_bounds__(256) void wprep_kernel(
        const float* __restrict__ W1, const float* __restrict__ W2,
        const float* __restrict__ W3, const float* __restrict__ W4,
        ushort* __restrict__ WTh, ushort* __restrict__ WTl) {
    int i = blockIdx.x * blockDim.x + threadIdx.x;   // 4*16384
    int l = i >> 14, r = i & 16383;
    int k = r >> 7, nn = r & 127;
    const float* W = (l == 0) ? W1 : (l == 1) ? W2 : (l == 2) ? W3 : W4;
    float w = W[k * HN + nn];
    uint hi = bf16rne(w);
    float fhi = __uint_as_float(hi << 16);
    uint lo = bf16rne(w - fhi);
    WTh[(size_t)l * 16384 + nn * HN + k] = (ushort)hi;
    WTl[(size_t)l * 16384 + nn * HN + k] = (ushort)lo;
}

// ---------------- pack: fp32 * onorm -> bf16 (layer-1 input) ----------------
__global__ __launch_bounds__(256) void pack_kernel(
        const float* __restrict__ in, const float* __restrict__ onorm,
        ushort* __restrict__ out, int total4) {
    int i = blockIdx.x * blockDim.x + threadIdx.x;
    if (i >= total4) return;
    float w = onorm[i >> 5];
    float4 v = ((const float4*)in)[i];
    ushort4 o = make_ushort4((ushort)bf16rne(v.x * w), (ushort)bf16rne(v.y * w),
                             (ushort)bf16rne(v.z * w), (ushort)bf16rne(v.w * w));
    *(ushort4*)(out + (size_t)i * 4) = o;
}

// ---------------- fused BN-apply + lrelu + onorm-fold + bf16 pack ----------------
__global__ __launch_bounds__(256) void bnpack_kernel(
        const float* __restrict__ in, ushort* __restrict__ out,
        const float* __restrict__ scale, const float* __restrict__ shift,
        const float* __restrict__ onorm, int total4) {
    int i = blockIdx.x * blockDim.x + threadIdx.x;
    if (i >= total4) return;
    int cp = (i & 31) << 2;
    float w = onorm[i >> 5];
    float4 v = ((const float4*)in)[i];
    float4 s = *(const float4*)(scale + cp);
    float4 t = *(const float4*)(shift + cp);
    float h0 = fmaf(v.x, s.x, t.x); h0 = (h0 >= 0.f) ? h0 : SLOPEV * h0;
    float h1 = fmaf(v.y, s.y, t.y); h1 = (h1 >= 0.f) ? h1 : SLOPEV * h1;
    float h2 = fmaf(v.z, s.z, t.z); h2 = (h2 >= 0.f) ? h2 : SLOPEV * h2;
    float h3 = fmaf(v.w, s.w, t.w); h3 = (h3 >= 0.f) ? h3 : SLOPEV * h3;
    ushort4 o = make_ushort4((ushort)bf16rne(h0 * w), (ushort)bf16rne(h1 * w),
                             (ushort)bf16rne(h2 * w), (ushort)bf16rne(h3 * w));
    *(ushort4*)(out + (size_t)i * 4) = o;
}

// ---------------- aggregation: one wave per dst node, bf16 in/out ----------------
__global__ __launch_bounds__(256) void agg_kernel(
        const uint* __restrict__ xb, uint* __restrict__ out,
        const int* __restrict__ srcs, const int* __restrict__ row_ptr,
        const float* __restrict__ inorm, int n) {
    int node = blockIdx.x * 4 + (threadIdx.x >> 6);
    if (node >= n) return;
    int lane = threadIdx.x & 63;
    int rp0 = row_ptr[node], rp1 = row_ptr[node + 1];
    float accx = 0.f, accy = 0.f;
    int j = rp0;
    for (; j + 1 < rp1; j += 2) {
        int s0 = srcs[j], s1 = srcs[j + 1];
        uint u0 = xb[(size_t)s0 * 64 + lane];
        uint u1 = xb[(size_t)s1 * 64 + lane];
        accx += __uint_as_float(u0 << 16) + __uint_as_float(u1 << 16);
        accy += __uint_as_float(u0 & 0xffff0000u) + __uint_as_float(u1 & 0xffff0000u);
    }
    if (j < rp1) {
        uint u0 = xb[(size_t)srcs[j] * 64 + lane];
        accx += __uint_as_float(u0 << 16);
        accy += __uint_as_float(u0 & 0xffff0000u);
    }
    float wi = inorm[node];
    uint o = bf16rne(accx * wi) | (bf16rne(accy * wi) << 16);
    out[(size_t)node * 64 + lane] = o;
}

// ---------------- MFMA GEMM with LDS-staged W (hi/lo), XOR-16 swizzle ----------------
// block = 4 waves x 16 rows; W(hi+lo) staged once per block into 64 KB LDS.
// chunk c (16B, k=c*8..c*8+7) of row n stored at uint4 idx n*16 + (c ^ (n&15)):
//   -> ds_read_b128 B-frags are 2-way bank aliased only (free).
template<int DO_STATS, int DO_LRELU, int DO_PACK>
__global__ __launch_bounds__(256) void gemm_mfma(
        const ushort* __restrict__ A, const uint4* __restrict__ WTh4,
        const uint4* __restrict__ WTl4, const float* __restrict__ bias,
        void* __restrict__ outv, float* __restrict__ colsum, float* __restrict__ colsq,
        const float* __restrict__ onorm, int n) {
    __shared__ uint4 sW[4096];   // [0,2048)=hi, [2048,4096)=lo — 64 KB
    int tid = threadIdx.x;
    #pragma unroll
    for (int it = 0; it < 8; it++) {
        int j = it * 256 + tid;              // chunk id 0..2047
        int nrow = j >> 4, c = j & 15;
        int sidx = nrow * 16 + (c ^ (nrow & 15));
        sW[sidx] = WTh4[j];
        sW[2048 + sidx] = WTl4[j];
    }
    __syncthreads();

    int wave = tid >> 6, lane = tid & 63;
    int l15 = lane & 15, quad = lane >> 4;
    int rbase = blockIdx.x * 64 + wave * 16;
    int arow = rbase + l15; if (arow > n - 1) arow = n - 1;   // clamped safe load

    bf16x8 af[4];
    #pragma unroll
    for (int kc = 0; kc < 4; kc++)
        af[kc] = *(const bf16x8*)(A + (size_t)arow * HN + kc * 32 + quad * 8);

    f32x4 acc[8];
    #pragma unroll
    for (int t = 0; t < 8; t++) acc[t] = (f32x4){0.f, 0.f, 0.f, 0.f};

    #pragma unroll
    for (int t = 0; t < 8; t++) {
        int nn = t * 16 + l15;
        int base = nn * 16, sw = nn & 15;
        #pragma unroll
        for (int kc = 0; kc < 4; kc++) {
            int c = kc * 4 + quad;
            bf16x8 bh = *(const bf16x8*)&sW[base + (c ^ sw)];
            acc[t] = __builtin_amdgcn_mfma_f32_16x16x32_bf16(af[kc], bh, acc[t], 0, 0, 0);
        }
        #pragma unroll
        for (int kc = 0; kc < 4; kc++) {
            int c = kc * 4 + quad;
            bf16x8 bl = *(const bf16x8*)&sW[2048 + base + (c ^ sw)];
            acc[t] = __builtin_amdgcn_mfma_f32_16x16x32_bf16(af[kc], bl, acc[t], 0, 0, 0);
        }
    }

    float sarr[8], qarr[8];
    #pragma unroll
    for (int t = 0; t < 8; t++) {
        int col = t * 16 + l15;
        float bv = bias[col];
        float s = 0.f, q = 0.f;
        #pragma unroll
        for (int i = 0; i < 4; i++) {
            int row = rbase + quad * 4 + i;
            float v = acc[t][i] + bv;
            if (DO_LRELU) v = (v >= 0.f) ? v : SLOPEV * v;
            if (row < n) {
                if (DO_PACK) {
                    ((ushort*)outv)[(size_t)row * HN + col] = (ushort)bf16rne(v * onorm[row]);
                } else {
                    ((float*)outv)[(size_t)row * HN + col] = v;
                }
                if (DO_STATS) { s += v; q += v * v; }
            }
        }
        if (DO_STATS) {
            s += __shfl_xor(s, 16); q += __shfl_xor(q, 16);
            s += __shfl_xor(s, 32); q += __shfl_xor(q, 32);
        }
        sarr[t] = s; qarr[t] = q;
    }

    if (DO_STATS) {
        __syncthreads();                      // all LDS W reads done — safe to alias
        float* sSum = (float*)sW;             // 512 floats
        float* sSq  = (float*)sW + 512;
        if (quad == 0) {
            #pragma unroll
            for (int t = 0; t < 8; t++) {
                sSum[wave * 128 + t * 16 + l15] = sarr[t];
                sSq [wave * 128 + t * 16 + l15] = qarr[t];
            }
        }
        __syncthreads();
        if (tid < 128) {
            float s = sSum[tid] + sSum[128 + tid] + sSum[256 + tid] + sSum[384 + tid];
            float q = sSq[tid] + sSq[128 + tid] + sSq[256 + tid] + sSq[384 + tid];
            atomicAdd(&colsum[tid], s);
            atomicAdd(&colsq[tid], q);
        }
    }
}

// ---------------- BN finalize ----------------
__global__ void bn_finalize(const float* __restrict__ colsum, const float* __restrict__ colsq,
                            const float* __restrict__ gamma, const float* __restrict__ beta,
                            float* __restrict__ scale, float* __restrict__ shift, int n) {
    int c = threadIdx.x;
    if (c < HN) {
        float inv = 1.f / (float)n;
        float mean = colsum[c] * inv;
        float var = colsq[c] * inv - mean * mean;
        if (var < 0.f) var = 0.f;
        float s = gamma[c] * rsqrtf(var + EPSV);
        scale[c] = s;
        shift[c] = beta[c] - mean * s;
    }
}

// ---------------- classifier: [n,128]fp32 @ [128,8]+bc ----------------
__global__ __launch_bounds__(256) void classifier_kernel(
        const float* __restrict__ A, const float* __restrict__ Wc,
        const float* __restrict__ bc, float* __restrict__ out, int n) {
    __shared__ float sW[HN * NC];
    __shared__ float sA[32 * 132];
    int tid = threadIdx.x;
    for (int i = tid; i < HN * NC; i += 256) sW[i] = Wc[i];
    int row0 = blockIdx.x * 32;
    for (int i = tid; i < 32 * 32; i += 256) {
        int r = i >> 5, c4 = (i & 31) << 2;
        float4 v = (row0 + r < n) ? *(const float4*)(A + (size_t)(row0 + r) * HN + c4)
                                  : make_float4(0.f, 0.f, 0.f, 0.f);
        *(float4*)&sA[r * 132 + c4] = v;
    }
    __syncthreads();
    int r = tid >> 3, c = tid & 7;
    float acc = 0.f;
    #pragma unroll 8
    for (int k = 0; k < HN; k++) acc = fmaf(sA[r * 132 + k], sW[k * NC + c], acc);
    int row = row0 + r;
    if (row < n) out[(size_t)row * NC + c] = acc + bc[c];
}

extern "C" void kernel_launch(void* const* d_in, const int* in_sizes, int n_in,
                              void* d_out, int out_size, void* d_ws, size_t ws_size,
                              hipStream_t stream) {
    const float* node_feat = (const float*)d_in[0];
    const int*   src    = (const int*)d_in[1];
    const int*   dst    = (const int*)d_in[2];
    const float* W1     = (const float*)d_in[3];
    const float* b1     = (const float*)d_in[4];
    const float* W2     = (const float*)d_in[5];
    const float* b2     = (const float*)d_in[6];
    const float* gamma1 = (const float*)d_in[7];
    const float* beta1  = (const float*)d_in[8];
    const float* gamma2 = (const float*)d_in[9];
    const float* beta2  = (const float*)d_in[10];
    const float* Wn1    = (const float*)d_in[11];
    const float* bn1    = (const float*)d_in[12];
    const float* Wn2    = (const float*)d_in[13];
    const float* bn2    = (const float*)d_in[14];
    const float* Wc     = (const float*)d_in[15];
    const float* bc     = (const float*)d_in[16];
    float* out = (float*)d_out;

    const int N = in_sizes[0] / HN;
    const int E = in_sizes[1];

    char* p = (char*)d_ws;
    float* bufA  = (float*)p; p += (size_t)N * HN * 4;   // lo: HbA(bf16), hi: Abf(bf16)
    float* bufB  = (float*)p; p += (size_t)N * HN * 4;   // fp32 gemm out / HbB(bf16)
    float* onorm = (float*)p; p += (size_t)N * 4;
    float* inorm = (float*)p; p += (size_t)N * 4;
    float* scale = (float*)p; p += HN * 4;
    float* shift = (float*)p; p += HN * 4;
    char* zbase = p;
    float* cs1 = (float*)p; p += HN * 4;
    float* cq1 = (float*)p; p += HN * 4;
    float* cs2 = (float*)p; p += HN * 4;
    float* cq2 = (float*)p; p += HN * 4;
    int* degO = (int*)p; p += (size_t)N * 4;
    int* cntI = (int*)p; p += (size_t)N * 4;
    size_t zbytes = (size_t)(p - zbase);
    int* row_ptr = (int*)p; p += (size_t)(N + 4) * 4;    // +4 pad keeps 16B alignment
    int* blockSums = (int*)p; p += 1024 * 4;
    int* rnk     = (int*)p; p += (size_t)E * 4;
    int* srcs    = (int*)p; p += (size_t)E * 4;
    ushort* WTh  = (ushort*)p; p += 4 * 16384 * 2;
    ushort* WTl  = (ushort*)p; p += 4 * 16384 * 2;
    if ((size_t)(p - (char*)d_ws) > ws_size) return;

    hipMemsetAsync(zbase, 0, zbytes, stream);

    int gE = (E + 255) / 256;
    int nb = (N + 1023) / 1024;
    rank_kernel<<<gE, 256, 0, stream>>>(src, dst, degO, cntI, rnk, E);
    scan_partial<<<nb, 256, 0, stream>>>(cntI, blockSums, N);
    scan_blocksums<<<1, 1024, 0, stream>>>(blockSums, nb);
    scan_final<<<nb, 256, 0, stream>>>(cntI, degO, blockSums, row_ptr, onorm, inorm, N, E);
    scatter_kernel<<<gE, 256, 0, stream>>>(src, dst, rnk, row_ptr, srcs, E);
    wprep_kernel<<<256, 256, 0, stream>>>(W1, W2, Wn1, Wn2, WTh, WTl);

    int gAgg = (N + 3) / 4;
    int gGemm = (N + 63) / 64;
    int gApply = (N * 32 + 255) / 256;

    ushort* HbA = (ushort*)bufA;
    ushort* Abf = (ushort*)bufA + (size_t)N * HN;
    ushort* HbB = (ushort*)bufB;

    // L1
    pack_kernel<<<gApply, 256, 0, stream>>>(node_feat, onorm, HbA, N * 32);
    agg_kernel<<<gAgg, 256, 0, stream>>>((const uint*)HbA, (uint*)Abf, srcs, row_ptr, inorm, N);
    gemm_mfma<1, 0, 0><<<gGemm, 256, 0, stream>>>(Abf, (const uint4*)WTh, (const uint4*)WTl,
                                                  b1, bufB, cs1, cq1, nullptr, N);
    bn_finalize<<<1, 128, 0, stream>>>(cs1, cq1, gamma1, beta1, scale, shift, N);
    bnpack_kernel<<<gApply, 256, 0, stream>>>(bufB, HbA, scale, shift, onorm, N * 32);

    // L2
    agg_kernel<<<gAgg, 256, 0, stream>>>((const uint*)HbA, (uint*)Abf, srcs, row_ptr, inorm, N);
    gemm_mfma<1, 0, 0><<<gGemm, 256, 0, stream>>>(Abf, (const uint4*)(WTh + 16384),
                                                  (const uint4*)(WTl + 16384),
                                                  b2, bufB, cs2, cq2, nullptr, N);
    bn_finalize<<<1, 128, 0, stream>>>(cs2, cq2, gamma2, beta2, scale, shift, N);
    bnpack_kernel<<<gApply, 256, 0, stream>>>(bufB, HbA, scale, shift, onorm, N * 32);

    // L3: gemm packs bf16*onorm directly
    agg_kernel<<<gAgg, 256, 0, stream>>>((const uint*)HbA, (uint*)Abf, srcs, row_ptr, inorm, N);
    gemm_mfma<0, 1, 1><<<gGemm, 256, 0, stream>>>(Abf, (const uint4*)(WTh + 2 * 16384),
                                                  (const uint4*)(WTl + 2 * 16384),
                                                  bn1, HbB, nullptr, nullptr, onorm, N);

    // L4
    agg_kernel<<<gAgg, 256, 0, stream>>>((const uint*)HbB, (uint*)Abf, srcs, row_ptr, inorm, N);
    gemm_mfma<0, 1, 0><<<gGemm, 256, 0, stream>>>(Abf, (const uint4*)(WTh + 3 * 16384),
                                                  (const uint4*)(WTl + 3 * 16384),
                                                  bn2, bufB, nullptr, nullptr, nullptr, N);
    classifier_kernel<<<(N + 31) / 32, 256, 0, stream>>>(bufB, Wc, bc, out, N);
}

// Round 6
// 757.609 us; speedup vs baseline: 1.4659x; 1.2179x over previous
//
#include <hip/hip_runtime.h>
#include <math.h>

#define HN 128
#define NC 8
#define EPSV 1e-5f
#define SLOPEV 0.01f

typedef __attribute__((ext_vector_type(4))) float f32x4;
typedef __attribute__((ext_vector_type(8))) short bf16x8;

__device__ __forceinline__ uint bf16rne(float f) {
    uint u = __float_as_uint(f);
    return (u + 0x7fffu + ((u >> 16) & 1u)) >> 16;
}

// ---------------- rank: degO histogram + in-count (doubles as rank), 4-edge ILP ----------------
__global__ __launch_bounds__(256) void rank_kernel(
        const int* __restrict__ src, const int* __restrict__ dst,
        int* __restrict__ degO, int* __restrict__ cntI,
        int* __restrict__ rnk, int E) {
    int base = blockIdx.x * 1024 + threadIdx.x;
    int s[4], d[4], r[4];
    #pragma unroll
    for (int k = 0; k < 4; k++) {
        int e = base + k * 256;
        if (e < E) { s[k] = src[e]; d[k] = dst[e]; }
    }
    #pragma unroll
    for (int k = 0; k < 4; k++) {
        int e = base + k * 256;
        if (e < E) atomicAdd(&degO[s[k]], 1);
    }
    #pragma unroll
    for (int k = 0; k < 4; k++) {
        int e = base + k * 256;
        if (e < E) r[k] = atomicAdd(&cntI[d[k]], 1);
    }
    #pragma unroll
    for (int k = 0; k < 4; k++) {
        int e = base + k * 256;
        if (e < E) rnk[e] = r[k];
    }
}

// ---------------- hierarchical exclusive scan (3 kernels) ----------------
__global__ __launch_bounds__(256) void scan_partial(const int* __restrict__ degI,
                                                    int* __restrict__ blockSums, int n) {
    __shared__ int sS[256];
    int tid = threadIdx.x;
    int base = blockIdx.x * 1024 + tid * 4;
    int s = 0;
    #pragma unroll
    for (int j = 0; j < 4; j++) {
        int idx = base + j;
        s += (idx < n) ? degI[idx] : 0;
    }
    sS[tid] = s;
    __syncthreads();
    for (int off = 128; off; off >>= 1) {
        if (tid < off) sS[tid] += sS[tid + off];
        __syncthreads();
    }
    if (tid == 0) blockSums[blockIdx.x] = sS[0];
}

__global__ __launch_bounds__(1024) void scan_blocksums(int* __restrict__ blockSums, int nb) {
    __shared__ int sS[1024];
    int tid = threadIdx.x;
    int v = (tid < nb) ? blockSums[tid] : 0;
    sS[tid] = v;
    __syncthreads();
    for (int off = 1; off < 1024; off <<= 1) {
        int t = (tid >= off) ? sS[tid - off] : 0;
        __syncthreads();
        sS[tid] += t;
        __syncthreads();
    }
    if (tid < nb) blockSums[tid] = sS[tid] - v;
}

// local scan + block offset -> row_ptr; also computes norms
__global__ __launch_bounds__(256) void scan_final(const int* __restrict__ degI,
                                                  const int* __restrict__ degO,
                                                  const int* __restrict__ blockSums,
                                                  int* __restrict__ row_ptr,
                                                  float* __restrict__ onorm,
                                                  float* __restrict__ inorm, int n, int E) {
    __shared__ int sS[256];
    int tid = threadIdx.x;
    int base = blockIdx.x * 1024 + tid * 4;
    int v[4];
    int tot = 0;
    #pragma unroll
    for (int j = 0; j < 4; j++) {
        int idx = base + j;
        int vv = (idx < n) ? degI[idx] : 0;
        v[j] = tot;
        tot += vv;
    }
    sS[tid] = tot;
    __syncthreads();
    for (int off = 1; off < 256; off <<= 1) {
        int t = (tid >= off) ? sS[tid - off] : 0;
        __syncthreads();
        sS[tid] += t;
        __syncthreads();
    }
    int tb = blockSums[blockIdx.x] + sS[tid] - tot;
    #pragma unroll
    for (int j = 0; j < 4; j++) {
        int idx = base + j;
        if (idx < n) {
            row_ptr[idx] = tb + v[j];
            float a = (float)degO[idx]; if (a < 1.f) a = 1.f;
            float b = (float)degI[idx]; if (b < 1.f) b = 1.f;
            onorm[idx] = rsqrtf(a);
            inorm[idx] = rsqrtf(b);
        }
    }
    if (blockIdx.x == 0 && tid == 0) row_ptr[n] = E;
}

// ---------------- atomic-free CSR scatter, 4-edge ILP ----------------
__global__ __launch_bounds__(256) void scatter_kernel(
        const int* __restrict__ src, const int* __restrict__ dst,
        const int* __restrict__ rnk, const int* __restrict__ row_ptr,
        int* __restrict__ srcs, int E) {
    int base = blockIdx.x * 1024 + threadIdx.x;
    int s[4], d[4], r[4], rp[4];
    #pragma unroll
    for (int k = 0; k < 4; k++) {
        int e = base + k * 256;
        if (e < E) { d[k] = dst[e]; r[k] = rnk[e]; s[k] = src[e]; }
    }
    #pragma unroll
    for (int k = 0; k < 4; k++) {
        int e = base + k * 256;
        if (e < E) rp[k] = row_ptr[d[k]];
    }
    #pragma unroll
    for (int k = 0; k < 4; k++) {
        int e = base + k * 256;
        if (e < E) srcs[rp[k] + r[k]] = s[k];
    }
}

// ---------------- weight prep: W[k][n] -> WT[n][k] hi/lo bf16 (4 layers) ----------------
__global__ __launch_bounds__(256) void wprep_kernel(
        const float* __restrict__ W1, const float* __restrict__ W2,
        const float* __restrict__ W3, const float* __restrict__ W4,
        ushort* __restrict__ WTh, ushort* __restrict__ WTl) {
    int i = blockIdx.x * blockDim.x + threadIdx.x;   // 4*16384
    int l = i >> 14, r = i & 16383;
    int k = r >> 7, nn = r & 127;
    const float* W = (l == 0) ? W1 : (l == 1) ? W2 : (l == 2) ? W3 : W4;
    float w = W[k * HN + nn];
    uint hi = bf16rne(w);
    float fhi = __uint_as_float(hi << 16);
    uint lo = bf16rne(w - fhi);
    WTh[(size_t)l * 16384 + nn * HN + k] = (ushort)hi;
    WTl[(size_t)l * 16384 + nn * HN + k] = (ushort)lo;
}

// ---------------- pack: fp32 * onorm -> bf16 (layer-1 input) ----------------
__global__ __launch_bounds__(256) void pack_kernel(
        const float* __restrict__ in, const float* __restrict__ onorm,
        ushort* __restrict__ out, int total4) {
    int i = blockIdx.x * blockDim.x + threadIdx.x;
    if (i >= total4) return;
    float w = onorm[i >> 5];
    float4 v = ((const float4*)in)[i];
    ushort4 o = make_ushort4((ushort)bf16rne(v.x * w), (ushort)bf16rne(v.y * w),
                             (ushort)bf16rne(v.z * w), (ushort)bf16rne(v.w * w));
    *(ushort4*)(out + (size_t)i * 4) = o;
}

// ---------------- fused BN-apply + lrelu + onorm-fold + bf16 pack ----------------
__global__ __launch_bounds__(256) void bnpack_kernel(
        const float* __restrict__ in, ushort* __restrict__ out,
        const float* __restrict__ scale, const float* __restrict__ shift,
        const float* __restrict__ onorm, int total4) {
    int i = blockIdx.x * blockDim.x + threadIdx.x;
    if (i >= total4) return;
    int cp = (i & 31) << 2;
    float w = onorm[i >> 5];
    float4 v = ((const float4*)in)[i];
    float4 s = *(const float4*)(scale + cp);
    float4 t = *(const float4*)(shift + cp);
    float h0 = fmaf(v.x, s.x, t.x); h0 = (h0 >= 0.f) ? h0 : SLOPEV * h0;
    float h1 = fmaf(v.y, s.y, t.y); h1 = (h1 >= 0.f) ? h1 : SLOPEV * h1;
    float h2 = fmaf(v.z, s.z, t.z); h2 = (h2 >= 0.f) ? h2 : SLOPEV * h2;
    float h3 = fmaf(v.w, s.w, t.w); h3 = (h3 >= 0.f) ? h3 : SLOPEV * h3;
    ushort4 o = make_ushort4((ushort)bf16rne(h0 * w), (ushort)bf16rne(h1 * w),
                             (ushort)bf16rne(h2 * w), (ushort)bf16rne(h3 * w));
    *(ushort4*)(out + (size_t)i * 4) = o;
}

// ---------------- aggregation: one wave per dst node, 4-edge unroll ----------------
__global__ __launch_bounds__(256) void agg_kernel(
        const uint* __restrict__ xb, uint* __restrict__ out,
        const int* __restrict__ srcs, const int* __restrict__ row_ptr,
        const float* __restrict__ inorm, int n) {
    int node = blockIdx.x * 4 + (threadIdx.x >> 6);
    if (node >= n) return;
    int lane = threadIdx.x & 63;
    int rp0 = row_ptr[node], rp1 = row_ptr[node + 1];
    float accx = 0.f, accy = 0.f;
    int j = rp0;
    for (; j + 3 < rp1; j += 4) {
        int s0 = srcs[j], s1 = srcs[j + 1], s2 = srcs[j + 2], s3 = srcs[j + 3];
        uint u0 = xb[(size_t)s0 * 64 + lane];
        uint u1 = xb[(size_t)s1 * 64 + lane];
        uint u2 = xb[(size_t)s2 * 64 + lane];
        uint u3 = xb[(size_t)s3 * 64 + lane];
        accx += __uint_as_float(u0 << 16) + __uint_as_float(u1 << 16)
              + __uint_as_float(u2 << 16) + __uint_as_float(u3 << 16);
        accy += __uint_as_float(u0 & 0xffff0000u) + __uint_as_float(u1 & 0xffff0000u)
              + __uint_as_float(u2 & 0xffff0000u) + __uint_as_float(u3 & 0xffff0000u);
    }
    for (; j < rp1; j++) {
        uint u0 = xb[(size_t)srcs[j] * 64 + lane];
        accx += __uint_as_float(u0 << 16);
        accy += __uint_as_float(u0 & 0xffff0000u);
    }
    float wi = inorm[node];
    uint o = bf16rne(accx * wi) | (bf16rne(accy * wi) << 16);
    out[(size_t)node * 64 + lane] = o;
}

// ---------------- MFMA GEMM, 512 threads / 128 rows per block ----------------
// 8 waves x 16 rows; W(hi+lo) staged once per block into 64 KB LDS, XOR-16 swizzle.
template<int DO_STATS, int DO_LRELU, int DO_PACK>
__global__ __launch_bounds__(512) void gemm_mfma(
        const ushort* __restrict__ A, const uint4* __restrict__ WTh4,
        const uint4* __restrict__ WTl4, const float* __restrict__ bias,
        void* __restrict__ outv, float* __restrict__ colsum, float* __restrict__ colsq,
        const float* __restrict__ onorm, int n) {
    __shared__ uint4 sW[4096];   // [0,2048)=hi, [2048,4096)=lo — 64 KB
    int tid = threadIdx.x;
    #pragma unroll
    for (int it = 0; it < 4; it++) {
        int j = it * 512 + tid;              // chunk id 0..2047
        int nrow = j >> 4, c = j & 15;
        int sidx = nrow * 16 + (c ^ (nrow & 15));
        sW[sidx] = WTh4[j];
        sW[2048 + sidx] = WTl4[j];
    }
    __syncthreads();

    int wave = tid >> 6, lane = tid & 63;
    int l15 = lane & 15, quad = lane >> 4;
    int rbase = blockIdx.x * 128 + wave * 16;
    int arow = rbase + l15; if (arow > n - 1) arow = n - 1;   // clamped safe load

    bf16x8 af[4];
    #pragma unroll
    for (int kc = 0; kc < 4; kc++)
        af[kc] = *(const bf16x8*)(A + (size_t)arow * HN + kc * 32 + quad * 8);

    f32x4 acc[8];
    #pragma unroll
    for (int t = 0; t < 8; t++) acc[t] = (f32x4){0.f, 0.f, 0.f, 0.f};

    #pragma unroll
    for (int t = 0; t < 8; t++) {
        int nn = t * 16 + l15;
        int base = nn * 16, sw = nn & 15;
        #pragma unroll
        for (int kc = 0; kc < 4; kc++) {
            int c = kc * 4 + quad;
            bf16x8 bh = *(const bf16x8*)&sW[base + (c ^ sw)];
            acc[t] = __builtin_amdgcn_mfma_f32_16x16x32_bf16(af[kc], bh, acc[t], 0, 0, 0);
        }
        #pragma unroll
        for (int kc = 0; kc < 4; kc++) {
            int c = kc * 4 + quad;
            bf16x8 bl = *(const bf16x8*)&sW[2048 + base + (c ^ sw)];
            acc[t] = __builtin_amdgcn_mfma_f32_16x16x32_bf16(af[kc], bl, acc[t], 0, 0, 0);
        }
    }

    float sarr[8], qarr[8];
    #pragma unroll
    for (int t = 0; t < 8; t++) {
        int col = t * 16 + l15;
        float bv = bias[col];
        float s = 0.f, q = 0.f;
        #pragma unroll
        for (int i = 0; i < 4; i++) {
            int row = rbase + quad * 4 + i;
            float v = acc[t][i] + bv;
            if (DO_LRELU) v = (v >= 0.f) ? v : SLOPEV * v;
            if (row < n) {
                if (DO_PACK) {
                    ((ushort*)outv)[(size_t)row * HN + col] = (ushort)bf16rne(v * onorm[row]);
                } else {
                    ((float*)outv)[(size_t)row * HN + col] = v;
                }
                if (DO_STATS) { s += v; q += v * v; }
            }
        }
        if (DO_STATS) {
            s += __shfl_xor(s, 16); q += __shfl_xor(q, 16);
            s += __shfl_xor(s, 32); q += __shfl_xor(q, 32);
        }
        sarr[t] = s; qarr[t] = q;
    }

    if (DO_STATS) {
        __syncthreads();                      // all LDS W reads done — safe to alias
        float* sSum = (float*)sW;             // 1024 floats
        float* sSq  = (float*)sW + 1024;
        if (quad == 0) {
            #pragma unroll
            for (int t = 0; t < 8; t++) {
                sSum[wave * 128 + t * 16 + l15] = sarr[t];
                sSq [wave * 128 + t * 16 + l15] = qarr[t];
            }
        }
        __syncthreads();
        if (tid < 128) {
            float s = 0.f, q = 0.f;
            #pragma unroll
            for (int w = 0; w < 8; w++) { s += sSum[w * 128 + tid]; q += sSq[w * 128 + tid]; }
            atomicAdd(&colsum[tid], s);
            atomicAdd(&colsq[tid], q);
        }
    }
}

// ---------------- BN finalize ----------------
__global__ void bn_finalize(const float* __restrict__ colsum, const float* __restrict__ colsq,
                            const float* __restrict__ gamma, const float* __restrict__ beta,
                            float* __restrict__ scale, float* __restrict__ shift, int n) {
    int c = threadIdx.x;
    if (c < HN) {
        float inv = 1.f / (float)n;
        float mean = colsum[c] * inv;
        float var = colsq[c] * inv - mean * mean;
        if (var < 0.f) var = 0.f;
        float s = gamma[c] * rsqrtf(var + EPSV);
        scale[c] = s;
        shift[c] = beta[c] - mean * s;
    }
}

// ---------------- classifier: [n,128]fp32 @ [128,8]+bc ----------------
__global__ __launch_bounds__(256) void classifier_kernel(
        const float* __restrict__ A, const float* __restrict__ Wc,
        const float* __restrict__ bc, float* __restrict__ out, int n) {
    __shared__ float sW[HN * NC];
    __shared__ float sA[32 * 132];
    int tid = threadIdx.x;
    for (int i = tid; i < HN * NC; i += 256) sW[i] = Wc[i];
    int row0 = blockIdx.x * 32;
    for (int i = tid; i < 32 * 32; i += 256) {
        int r = i >> 5, c4 = (i & 31) << 2;
        float4 v = (row0 + r < n) ? *(const float4*)(A + (size_t)(row0 + r) * HN + c4)
                                  : make_float4(0.f, 0.f, 0.f, 0.f);
        *(float4*)&sA[r * 132 + c4] = v;
    }
    __syncthreads();
    int r = tid >> 3, c = tid & 7;
    float acc = 0.f;
    #pragma unroll 8
    for (int k = 0; k < HN; k++) acc = fmaf(sA[r * 132 + k], sW[k * NC + c], acc);
    int row = row0 + r;
    if (row < n) out[(size_t)row * NC + c] = acc + bc[c];
}

extern "C" void kernel_launch(void* const* d_in, const int* in_sizes, int n_in,
                              void* d_out, int out_size, void* d_ws, size_t ws_size,
                              hipStream_t stream) {
    const float* node_feat = (const float*)d_in[0];
    const int*   src    = (const int*)d_in[1];
    const int*   dst    = (const int*)d_in[2];
    const float* W1     = (const float*)d_in[3];
    const float* b1     = (const float*)d_in[4];
    const float* W2     = (const float*)d_in[5];
    const float* b2     = (const float*)d_in[6];
    const float* gamma1 = (const float*)d_in[7];
    const float* beta1  = (const float*)d_in[8];
    const float* gamma2 = (const float*)d_in[9];
    const float* beta2  = (const float*)d_in[10];
    const float* Wn1    = (const float*)d_in[11];
    const float* bn1    = (const float*)d_in[12];
    const float* Wn2    = (const float*)d_in[13];
    const float* bn2    = (const float*)d_in[14];
    const float* Wc     = (const float*)d_in[15];
    const float* bc     = (const float*)d_in[16];
    float* out = (float*)d_out;

    const int N = in_sizes[0] / HN;
    const int E = in_sizes[1];

    char* p = (char*)d_ws;
    float* bufA  = (float*)p; p += (size_t)N * HN * 4;   // lo: HbA(bf16), hi: Abf(bf16)
    float* bufB  = (float*)p; p += (size_t)N * HN * 4;   // fp32 gemm out / HbB(bf16)
    float* onorm = (float*)p; p += (size_t)N * 4;
    float* inorm = (float*)p; p += (size_t)N * 4;
    float* scale = (float*)p; p += HN * 4;
    float* shift = (float*)p; p += HN * 4;
    char* zbase = p;
    float* cs1 = (float*)p; p += HN * 4;
    float* cq1 = (float*)p; p += HN * 4;
    float* cs2 = (float*)p; p += HN * 4;
    float* cq2 = (float*)p; p += HN * 4;
    int* degO = (int*)p; p += (size_t)N * 4;
    int* cntI = (int*)p; p += (size_t)N * 4;
    size_t zbytes = (size_t)(p - zbase);
    int* row_ptr = (int*)p; p += (size_t)(N + 4) * 4;
    int* blockSums = (int*)p; p += 1024 * 4;
    int* rnk     = (int*)p; p += (size_t)E * 4;
    int* srcs    = (int*)p; p += (size_t)E * 4;
    ushort* WTh  = (ushort*)p; p += 4 * 16384 * 2;
    ushort* WTl  = (ushort*)p; p += 4 * 16384 * 2;
    if ((size_t)(p - (char*)d_ws) > ws_size) return;

    hipMemsetAsync(zbase, 0, zbytes, stream);

    int gE4 = (E + 1023) / 1024;
    int nb = (N + 1023) / 1024;
    rank_kernel<<<gE4, 256, 0, stream>>>(src, dst, degO, cntI, rnk, E);
    scan_partial<<<nb, 256, 0, stream>>>(cntI, blockSums, N);
    scan_blocksums<<<1, 1024, 0, stream>>>(blockSums, nb);
    scan_final<<<nb, 256, 0, stream>>>(cntI, degO, blockSums, row_ptr, onorm, inorm, N, E);
    scatter_kernel<<<gE4, 256, 0, stream>>>(src, dst, rnk, row_ptr, srcs, E);
    wprep_kernel<<<256, 256, 0, stream>>>(W1, W2, Wn1, Wn2, WTh, WTl);

    int gAgg = (N + 3) / 4;
    int gGemm = (N + 127) / 128;
    int gApply = (N * 32 + 255) / 256;

    ushort* HbA = (ushort*)bufA;
    ushort* Abf = (ushort*)bufA + (size_t)N * HN;
    ushort* HbB = (ushort*)bufB;

    // L1
    pack_kernel<<<gApply, 256, 0, stream>>>(node_feat, onorm, HbA, N * 32);
    agg_kernel<<<gAgg, 256, 0, stream>>>((const uint*)HbA, (uint*)Abf, srcs, row_ptr, inorm, N);
    gemm_mfma<1, 0, 0><<<gGemm, 512, 0, stream>>>(Abf, (const uint4*)WTh, (const uint4*)WTl,
                                                  b1, bufB, cs1, cq1, nullptr, N);
    bn_finalize<<<1, 128, 0, stream>>>(cs1, cq1, gamma1, beta1, scale, shift, N);
    bnpack_kernel<<<gApply, 256, 0, stream>>>(bufB, HbA, scale, shift, onorm, N * 32);

    // L2
    agg_kernel<<<gAgg, 256, 0, stream>>>((const uint*)HbA, (uint*)Abf, srcs, row_ptr, inorm, N);
    gemm_mfma<1, 0, 0><<<gGemm, 512, 0, stream>>>(Abf, (const uint4*)(WTh + 16384),
                                                  (const uint4*)(WTl + 16384),
                                                  b2, bufB, cs2, cq2, nullptr, N);
    bn_finalize<<<1, 128, 0, stream>>>(cs2, cq2, gamma2, beta2, scale, shift, N);
    bnpack_kernel<<<gApply, 256, 0, stream>>>(bufB, HbA, scale, shift, onorm, N * 32);

    // L3: gemm packs bf16*onorm directly
    agg_kernel<<<gAgg, 256, 0, stream>>>((const uint*)HbA, (uint*)Abf, srcs, row_ptr, inorm, N);
    gemm_mfma<0, 1, 1><<<gGemm, 512, 0, stream>>>(Abf, (const uint4*)(WTh + 2 * 16384),
                                                  (const uint4*)(WTl + 2 * 16384),
                                                  bn1, HbB, nullptr, nullptr, onorm, N);

    // L4
    agg_kernel<<<gAgg, 256, 0, stream>>>((const uint*)HbB, (uint*)Abf, srcs, row_ptr, inorm, N);
    gemm_mfma<0, 1, 0><<<gGemm, 512, 0, stream>>>(Abf, (const uint4*)(WTh + 3 * 16384),
                                                  (const uint4*)(WTl + 3 * 16384),
                                                  bn2, bufB, nullptr, nullptr, nullptr, N);
    classifier_kernel<<<(N + 31) / 32, 256, 0, stream>>>(bufB, Wc, bc, out, N);
}